// Round 2
// baseline (1546.819 us; speedup 1.0000x reference)
//
#include <hip/hip_runtime.h>

// Problem constants
#define Bb 2
#define Ll 2048
#define Ee 2048
#define Hh 16
#define Dd 128
#define BL (Bb * Ll)   // 4096
#define LOSCALE 1024.0f
#define INV_LOSCALE (1.0f / 1024.0f)

typedef float f32x4 __attribute__((ext_vector_type(4)));
typedef _Float16 f16x8 __attribute__((ext_vector_type(8)));

// ---------------------------------------------------------------------------
// f32 -> f16 plain convert (4 elems / thread)
// ---------------------------------------------------------------------------
__global__ __launch_bounds__(256) void cvt_f32_f16(const float* __restrict__ in,
                                                   _Float16* __restrict__ out, int n4) {
  int i = blockIdx.x * 256 + threadIdx.x;
  if (i < n4) {
    float4 f = ((const float4*)in)[i];
    _Float16 o[4] = {(_Float16)f.x, (_Float16)f.y, (_Float16)f.z, (_Float16)f.w};
    ((uint2*)out)[i] = *(uint2*)o;
  }
}

// ---------------------------------------------------------------------------
// f32 -> split fp16: hi = rn(x), lo = rn((x - hi) * 1024)  (ε² precision)
// ---------------------------------------------------------------------------
__global__ __launch_bounds__(256) void cvt_split(const float* __restrict__ in,
                                                 _Float16* __restrict__ hi,
                                                 _Float16* __restrict__ lo, int n4) {
  int i = blockIdx.x * 256 + threadIdx.x;
  if (i < n4) {
    float4 f = ((const float4*)in)[i];
    float fa[4] = {f.x, f.y, f.z, f.w};
    _Float16 h[4], l[4];
    for (int j = 0; j < 4; ++j) {
      h[j] = (_Float16)fa[j];
      l[j] = (_Float16)((fa[j] - (float)h[j]) * LOSCALE);
    }
    ((uint2*)hi)[i] = *(uint2*)h;
    ((uint2*)lo)[i] = *(uint2*)l;
  }
}

// ---------------------------------------------------------------------------
// GEMM:  C = (ACC ? C : 0) + outscale * (A[M,K] @ Bw[N,K]^T)
// A, Bw fp16; fp32 MFMA accumulation. 128x128 tile, BK=64, 4 waves.
// ---------------------------------------------------------------------------
template <typename OutT, bool ACC>
__global__ __launch_bounds__(256) void gemm_bt(const _Float16* __restrict__ A,
                                               const _Float16* __restrict__ Bw,
                                               OutT* __restrict__ C, int M, int N, int K,
                                               float outscale) {
  __shared__ _Float16 As[128][64];
  __shared__ _Float16 Bs[128][64];
  const int tid = threadIdx.x;
  const int wave = tid >> 6, lane = tid & 63;
  const int quad = lane >> 4, l16 = lane & 15;
  const int bm = blockIdx.y * 128, bn = blockIdx.x * 128;
  const int wm = (wave >> 1) * 64, wn = (wave & 1) * 64;

  f32x4 acc[4][4] = {};

  for (int k0 = 0; k0 < K; k0 += 64) {
    for (int c = 0; c < 4; ++c) {
      int chunk = tid + c * 256;
      int row = chunk >> 3;
      int col = (chunk & 7) * 8;
      *(uint4*)&As[row][col] = *(const uint4*)&A[(size_t)(bm + row) * K + k0 + col];
      *(uint4*)&Bs[row][col] = *(const uint4*)&Bw[(size_t)(bn + row) * K + k0 + col];
    }
    __syncthreads();
    for (int ks = 0; ks < 2; ++ks) {
      f16x8 af[4], bf[4];
      for (int mt = 0; mt < 4; ++mt)
        af[mt] = *(const f16x8*)&As[wm + mt * 16 + l16][ks * 32 + quad * 8];
      for (int nt = 0; nt < 4; ++nt)
        bf[nt] = *(const f16x8*)&Bs[wn + nt * 16 + l16][ks * 32 + quad * 8];
      for (int mt = 0; mt < 4; ++mt)
        for (int nt = 0; nt < 4; ++nt)
          acc[mt][nt] = __builtin_amdgcn_mfma_f32_16x16x32_f16(af[mt], bf[nt], acc[mt][nt], 0, 0, 0);
    }
    __syncthreads();
  }

  for (int mt = 0; mt < 4; ++mt)
    for (int nt = 0; nt < 4; ++nt)
      for (int r = 0; r < 4; ++r) {
        int m = bm + wm + mt * 16 + quad * 4 + r;
        int n = bn + wn + nt * 16 + l16;
        size_t idx = (size_t)m * N + n;
        float v = acc[mt][nt][r] * outscale;
        if (ACC) v += (float)C[idx];
        C[idx] = (OutT)v;
      }
}

// ---------------------------------------------------------------------------
// Fused RMSNorm (fp32) + rotary + outmul -> split fp16 (hi, lo*1024)
// One wave per (b,l,h) row; thread t handles pair (2t, 2t+1).
// ---------------------------------------------------------------------------
__global__ __launch_bounds__(256) void rmsrope(const float* __restrict__ raw,
                                               const float* __restrict__ scale,
                                               const float* __restrict__ rope,
                                               _Float16* __restrict__ outh,
                                               _Float16* __restrict__ outl, float outmul) {
  int row = blockIdx.x * 4 + (threadIdx.x >> 6);
  int t = threadIdx.x & 63;
  float2 x = *(const float2*)&raw[(size_t)row * Dd + 2 * t];
  float ss = x.x * x.x + x.y * x.y;
  for (int off = 1; off < 64; off <<= 1) ss += __shfl_xor(ss, off);
  float inv = rsqrtf(ss * (1.0f / Dd) + 1e-6f);
  float2 sc = *(const float2*)&scale[2 * t];
  float y0 = x.x * inv * sc.x;
  float y1 = x.y * inv * sc.y;
  int bl = row >> 4;  // row / H
  float2 cs = *(const float2*)&rope[(size_t)bl * Dd + 2 * t];
  float r0 = (y0 * cs.x - y1 * cs.y) * outmul;
  float r1 = (y1 * cs.x + y0 * cs.y) * outmul;
  _Float16 h[2] = {(_Float16)r0, (_Float16)r1};
  _Float16 l[2] = {(_Float16)((r0 - (float)h[0]) * LOSCALE),
                   (_Float16)((r1 - (float)h[1]) * LOSCALE)};
  *(uint*)&outh[(size_t)row * Dd + 2 * t] = *(uint*)h;
  *(uint*)&outl[(size_t)row * Dd + 2 * t] = *(uint*)l;
}

// ---------------------------------------------------------------------------
// Flash attention with split-fp16 QK^T (S = qh·kh + (qh·kl + ql·kh)/1024).
// One block = (b, h, 64-row q tile). Q fragments loaded straight from global
// into registers (A-layout); K hi/lo + V^T staged in LDS. Online softmax fp32.
// P through wave-private LDS (C->A layout). Out fp16 [B,L,H,D].
// ---------------------------------------------------------------------------
__global__ __launch_bounds__(256) void attn(const _Float16* __restrict__ Qh_,
                                            const _Float16* __restrict__ Ql_,
                                            const _Float16* __restrict__ Kh_,
                                            const _Float16* __restrict__ Kl_,
                                            const _Float16* __restrict__ V,
                                            const float* __restrict__ bias,
                                            _Float16* __restrict__ O) {
  __shared__ _Float16 Ksh[64][128];
  __shared__ _Float16 Ksl[64][128];
  __shared__ _Float16 Vt[128][64];  // Vt[d][k]
  __shared__ _Float16 Ps[64][64];

  const int tid = threadIdx.x;
  const int wave = tid >> 6, lane = tid & 63;
  const int quad = lane >> 4, l16 = lane & 15;
  const int q0 = blockIdx.x * 64;
  const int h = blockIdx.y, b = blockIdx.z;

  // Q fragments (A-layout: row = wave*16+l16, cols ks*32+quad*8..+8)
  f16x8 aqh[4], aql[4];
  {
    size_t qrow = (((size_t)b * Ll + q0 + wave * 16 + l16) * Hh + h) * Dd;
    for (int ks = 0; ks < 4; ++ks) {
      aqh[ks] = *(const f16x8*)&Qh_[qrow + ks * 32 + quad * 8];
      aql[ks] = *(const f16x8*)&Ql_[qrow + ks * 32 + quad * 8];
    }
  }

  f32x4 o_acc[8] = {};
  float m_r[4], l_r[4];
  for (int r = 0; r < 4; ++r) { m_r[r] = -1e30f; l_r[r] = 0.f; }

  for (int kt = 0; kt < Ll / 64; ++kt) {
    int k0 = kt * 64;
    for (int c = 0; c < 4; ++c) {
      int chunk = tid + c * 256;
      int row = chunk >> 4;
      int col = (chunk & 15) * 8;
      size_t g = (((size_t)b * Ll + k0 + row) * Hh + h) * Dd + col;
      *(uint4*)&Ksh[row][col] = *(const uint4*)&Kh_[g];
      *(uint4*)&Ksl[row][col] = *(const uint4*)&Kl_[g];
      uint4 vv = *(const uint4*)&V[g];
      _Float16 tmp[8];
      *(uint4*)tmp = vv;
      for (int j = 0; j < 8; ++j) Vt[col + j][row] = tmp[j];
    }
    __syncthreads();

    // S = Q @ K^T with hi/lo correction
    f32x4 s_hh[4] = {}, s_cr[4] = {};
    for (int ks = 0; ks < 4; ++ks) {
      for (int nt = 0; nt < 4; ++nt) {
        f16x8 bkh = *(const f16x8*)&Ksh[nt * 16 + l16][ks * 32 + quad * 8];
        f16x8 bkl = *(const f16x8*)&Ksl[nt * 16 + l16][ks * 32 + quad * 8];
        s_hh[nt] = __builtin_amdgcn_mfma_f32_16x16x32_f16(aqh[ks], bkh, s_hh[nt], 0, 0, 0);
        s_cr[nt] = __builtin_amdgcn_mfma_f32_16x16x32_f16(aqh[ks], bkl, s_cr[nt], 0, 0, 0);
        s_cr[nt] = __builtin_amdgcn_mfma_f32_16x16x32_f16(aql[ks], bkh, s_cr[nt], 0, 0, 0);
      }
    }
    f32x4 s_acc[4];
    for (int nt = 0; nt < 4; ++nt)
      for (int r = 0; r < 4; ++r) {
        int gq = q0 + wave * 16 + quad * 4 + r;
        int gk = k0 + nt * 16 + l16;
        s_acc[nt][r] = s_hh[nt][r] + s_cr[nt][r] * INV_LOSCALE +
                       bias[((size_t)b * Ll + gq) * Ll + gk];
      }

    // online softmax
    float alpha[4];
    for (int r = 0; r < 4; ++r) {
      float x = fmaxf(fmaxf(s_acc[0][r], s_acc[1][r]), fmaxf(s_acc[2][r], s_acc[3][r]));
      for (int off = 1; off < 16; off <<= 1) x = fmaxf(x, __shfl_xor(x, off));
      float mn = fmaxf(m_r[r], x);
      alpha[r] = __expf(m_r[r] - mn);
      m_r[r] = mn;
    }
    for (int r = 0; r < 4; ++r) {
      float sum = 0.f;
      for (int nt = 0; nt < 4; ++nt) {
        float p = __expf(s_acc[nt][r] - m_r[r]);
        sum += p;
        Ps[wave * 16 + quad * 4 + r][nt * 16 + l16] = (_Float16)p;
      }
      for (int off = 1; off < 16; off <<= 1) sum += __shfl_xor(sum, off);
      l_r[r] = l_r[r] * alpha[r] + sum;
    }
    for (int ot = 0; ot < 8; ++ot)
      for (int r = 0; r < 4; ++r) o_acc[ot][r] *= alpha[r];
    // O += P @ V  (wave-private Ps round-trip)
    for (int ks = 0; ks < 2; ++ks) {
      f16x8 ap = *(const f16x8*)&Ps[wave * 16 + l16][ks * 32 + quad * 8];
      for (int ot = 0; ot < 8; ++ot) {
        f16x8 bv = *(const f16x8*)&Vt[ot * 16 + l16][ks * 32 + quad * 8];
        o_acc[ot] = __builtin_amdgcn_mfma_f32_16x16x32_f16(ap, bv, o_acc[ot], 0, 0, 0);
      }
    }
    __syncthreads();
  }

  for (int ot = 0; ot < 8; ++ot)
    for (int r = 0; r < 4; ++r) {
      int m = wave * 16 + quad * 4 + r;
      int d = ot * 16 + l16;
      float v = o_acc[ot][r] / l_r[r];
      O[(((size_t)b * Ll + q0 + m) * Hh + h) * Dd + d] = (_Float16)v;
    }
}

// ---------------------------------------------------------------------------
extern "C" void kernel_launch(void* const* d_in, const int* in_sizes, int n_in,
                              void* d_out, int out_size, void* d_ws, size_t ws_size,
                              hipStream_t stream) {
  const float* inputs_q  = (const float*)d_in[0];
  const float* inputs_kv = (const float*)d_in[1];
  const float* bias      = (const float*)d_in[2];
  const float* rope_q    = (const float*)d_in[3];
  const float* rope_k    = (const float*)d_in[4];
  const float* Wq        = (const float*)d_in[5];
  const float* Wk        = (const float*)d_in[6];
  const float* Wv        = (const float*)d_in[7];
  const float* Wo        = (const float*)d_in[8];
  const float* q_scale   = (const float*)d_in[9];
  const float* k_scale   = (const float*)d_in[10];
  float* out = (float*)d_out;

  char* ws = (char*)d_ws;
  size_t o = 0;
  auto alloc = [&](size_t bytes) {
    char* p = ws + o;
    o += (bytes + 255) & ~(size_t)255;
    return p;
  };
  const size_t szX16 = (size_t)BL * Ee * 2;   // 16 MB
  const size_t szW16 = (size_t)Ee * Ee * 2;   // 8 MB
  _Float16* Xq_hi  = (_Float16*)alloc(szX16);
  _Float16* Xq_lo  = (_Float16*)alloc(szX16);
  _Float16* Xkv_hi = (_Float16*)alloc(szX16);
  _Float16* Xkv_lo = (_Float16*)alloc(szX16);
  _Float16* Wq_hi  = (_Float16*)alloc(szW16);
  _Float16* Wq_lo  = (_Float16*)alloc(szW16);
  _Float16* Wk_hi  = (_Float16*)alloc(szW16);
  _Float16* Wk_lo  = (_Float16*)alloc(szW16);
  _Float16* Wv_hi  = (_Float16*)alloc(szW16);
  _Float16* Wo_hi  = (_Float16*)alloc(szW16);
  float* Qraw = (float*)alloc((size_t)BL * Ee * 4);   // 32 MB
  float* Kraw = (float*)alloc((size_t)BL * Ee * 4);   // 32 MB
  _Float16* V16 = (_Float16*)alloc(szX16);
  // aliases (stream-ordered reuse; lifetimes disjoint)
  _Float16* Q16h = Xq_hi;            // after Q-projection GEMMs, Xq is dead
  _Float16* Q16l = Xq_lo;
  _Float16* K16h = Xkv_hi;           // after K/V GEMMs, Xkv is dead
  _Float16* K16l = Xkv_lo;
  _Float16* X16  = (_Float16*)Qraw;  // after rmsrope, Qraw is dead

  const int nX4 = BL * Ee / 4;   // 2,097,152
  const int nW4 = Ee * Ee / 4;   // 1,048,576
  cvt_split<<<nX4 / 256, 256, 0, stream>>>(inputs_q, Xq_hi, Xq_lo, nX4);
  cvt_split<<<nX4 / 256, 256, 0, stream>>>(inputs_kv, Xkv_hi, Xkv_lo, nX4);
  cvt_split<<<nW4 / 256, 256, 0, stream>>>(Wq, Wq_hi, Wq_lo, nW4);
  cvt_split<<<nW4 / 256, 256, 0, stream>>>(Wk, Wk_hi, Wk_lo, nW4);
  cvt_f32_f16<<<nW4 / 256, 256, 0, stream>>>(Wv, Wv_hi, nW4);
  cvt_f32_f16<<<nW4 / 256, 256, 0, stream>>>(Wo, Wo_hi, nW4);

  dim3 gblk(Ee / 128, BL / 128);  // (16, 32)
  // Q projection: hi*hi + (hi*lo + lo*hi)/1024
  gemm_bt<float, false><<<gblk, 256, 0, stream>>>(Xq_hi, Wq_hi, Qraw, BL, Ee, Ee, 1.0f);
  gemm_bt<float, true ><<<gblk, 256, 0, stream>>>(Xq_hi, Wq_lo, Qraw, BL, Ee, Ee, INV_LOSCALE);
  gemm_bt<float, true ><<<gblk, 256, 0, stream>>>(Xq_lo, Wq_hi, Qraw, BL, Ee, Ee, INV_LOSCALE);
  // K projection
  gemm_bt<float, false><<<gblk, 256, 0, stream>>>(Xkv_hi, Wk_hi, Kraw, BL, Ee, Ee, 1.0f);
  gemm_bt<float, true ><<<gblk, 256, 0, stream>>>(Xkv_hi, Wk_lo, Kraw, BL, Ee, Ee, INV_LOSCALE);
  gemm_bt<float, true ><<<gblk, 256, 0, stream>>>(Xkv_lo, Wk_hi, Kraw, BL, Ee, Ee, INV_LOSCALE);
  // V projection (plain fp16 — not logit-critical)
  gemm_bt<_Float16, false><<<gblk, 256, 0, stream>>>(Xkv_hi, Wv_hi, V16, BL, Ee, Ee, 1.0f);

  rmsrope<<<BL * Hh / 4, 256, 0, stream>>>(Qraw, q_scale, rope_q, Q16h, Q16l, sqrtf((float)Dd));
  rmsrope<<<BL * Hh / 4, 256, 0, stream>>>(Kraw, k_scale, rope_k, K16h, K16l, 1.0f);

  attn<<<dim3(Ll / 64, Hh, Bb), 256, 0, stream>>>(Q16h, Q16l, K16h, K16l, V16, bias, X16);

  gemm_bt<float, false><<<gblk, 256, 0, stream>>>(X16, Wo_hi, out, BL, Ee, Ee, 1.0f);
}

// Round 3
// 935.838 us; speedup vs baseline: 1.6529x; 1.6529x over previous
//
#include <hip/hip_runtime.h>

// Problem constants
#define Bb 2
#define Ll 2048
#define Ee 2048
#define Hh 16
#define Dd 128
#define BL (Bb * Ll)   // 4096
#define LOSCALE 1024.0f
#define INV_LOSCALE (1.0f / 1024.0f)

typedef float f32x4 __attribute__((ext_vector_type(4)));
typedef _Float16 f16x8 __attribute__((ext_vector_type(8)));

// ---------------------------------------------------------------------------
// f32 -> f16 plain convert (4 elems / thread)
// ---------------------------------------------------------------------------
__global__ __launch_bounds__(256) void cvt_f32_f16(const float* __restrict__ in,
                                                   _Float16* __restrict__ out, int n4) {
  int i = blockIdx.x * 256 + threadIdx.x;
  if (i < n4) {
    float4 f = ((const float4*)in)[i];
    _Float16 o[4] = {(_Float16)f.x, (_Float16)f.y, (_Float16)f.z, (_Float16)f.w};
    ((uint2*)out)[i] = *(uint2*)o;
  }
}

// ---------------------------------------------------------------------------
// f32 -> split fp16: hi = rn(x), lo = rn((x - hi) * 1024)  (eps^2 precision)
// ---------------------------------------------------------------------------
__global__ __launch_bounds__(256) void cvt_split(const float* __restrict__ in,
                                                 _Float16* __restrict__ hi,
                                                 _Float16* __restrict__ lo, int n4) {
  int i = blockIdx.x * 256 + threadIdx.x;
  if (i < n4) {
    float4 f = ((const float4*)in)[i];
    float fa[4] = {f.x, f.y, f.z, f.w};
    _Float16 h[4], l[4];
    for (int j = 0; j < 4; ++j) {
      h[j] = (_Float16)fa[j];
      l[j] = (_Float16)((fa[j] - (float)h[j]) * LOSCALE);
    }
    ((uint2*)hi)[i] = *(uint2*)h;
    ((uint2*)lo)[i] = *(uint2*)l;
  }
}

// ---------------------------------------------------------------------------
// Plain GEMM:  C[M,N] = A[M,K] @ Bw[N,K]^T.  LDS rows padded to 72 halfs
// (stride 36 dw -> bank 4*(l16+quad) pattern, uniform across windows).
// ---------------------------------------------------------------------------
template <typename OutT>
__global__ __launch_bounds__(256) void gemm_bt(const _Float16* __restrict__ A,
                                               const _Float16* __restrict__ Bw,
                                               OutT* __restrict__ C, int M, int N, int K) {
  __shared__ _Float16 As[128][72];
  __shared__ _Float16 Bs[128][72];
  const int tid = threadIdx.x;
  const int wave = tid >> 6, lane = tid & 63;
  const int quad = lane >> 4, l16 = lane & 15;
  const int bm = blockIdx.y * 128, bn = blockIdx.x * 128;
  const int wm = (wave >> 1) * 64, wn = (wave & 1) * 64;

  f32x4 acc[4][4] = {};

  for (int k0 = 0; k0 < K; k0 += 64) {
    for (int c = 0; c < 4; ++c) {
      int chunk = tid + c * 256;
      int row = chunk >> 3;
      int col = (chunk & 7) * 8;
      *(uint4*)&As[row][col] = *(const uint4*)&A[(size_t)(bm + row) * K + k0 + col];
      *(uint4*)&Bs[row][col] = *(const uint4*)&Bw[(size_t)(bn + row) * K + k0 + col];
    }
    __syncthreads();
    for (int ks = 0; ks < 2; ++ks) {
      f16x8 af[4], bf[4];
      for (int mt = 0; mt < 4; ++mt)
        af[mt] = *(const f16x8*)&As[wm + mt * 16 + l16][ks * 32 + quad * 8];
      for (int nt = 0; nt < 4; ++nt)
        bf[nt] = *(const f16x8*)&Bs[wn + nt * 16 + l16][ks * 32 + quad * 8];
      for (int mt = 0; mt < 4; ++mt)
        for (int nt = 0; nt < 4; ++nt)
          acc[mt][nt] = __builtin_amdgcn_mfma_f32_16x16x32_f16(af[mt], bf[nt], acc[mt][nt], 0, 0, 0);
    }
    __syncthreads();
  }

  for (int mt = 0; mt < 4; ++mt)
    for (int nt = 0; nt < 4; ++nt)
      for (int r = 0; r < 4; ++r) {
        int m = bm + wm + mt * 16 + quad * 4 + r;
        int n = bn + wn + nt * 16 + l16;
        C[(size_t)m * N + n] = (OutT)acc[mt][nt][r];
      }
}

// ---------------------------------------------------------------------------
// Fused split GEMM:  C = Ah@Bh^T + (Ah@Bl^T + Al@Bh^T)/1024   (one launch,
// no C read-modify-write). 4 padded LDS tiles, 3 MFMAs per fragment pair.
// ---------------------------------------------------------------------------
template <typename OutT>
__global__ __launch_bounds__(256) void gemm_bt_split(
    const _Float16* __restrict__ Ah, const _Float16* __restrict__ Al,
    const _Float16* __restrict__ Bh, const _Float16* __restrict__ Bl,
    OutT* __restrict__ C, int M, int N, int K) {
  __shared__ _Float16 Ash[128][72];
  __shared__ _Float16 Asl[128][72];
  __shared__ _Float16 Bsh[128][72];
  __shared__ _Float16 Bsl[128][72];
  const int tid = threadIdx.x;
  const int wave = tid >> 6, lane = tid & 63;
  const int quad = lane >> 4, l16 = lane & 15;
  const int bm = blockIdx.y * 128, bn = blockIdx.x * 128;
  const int wm = (wave >> 1) * 64, wn = (wave & 1) * 64;

  f32x4 acc_hh[4][4] = {};
  f32x4 acc_cr[4][4] = {};

  for (int k0 = 0; k0 < K; k0 += 64) {
    for (int c = 0; c < 4; ++c) {
      int chunk = tid + c * 256;
      int row = chunk >> 3;
      int col = (chunk & 7) * 8;
      size_t ga = (size_t)(bm + row) * K + k0 + col;
      size_t gb = (size_t)(bn + row) * K + k0 + col;
      *(uint4*)&Ash[row][col] = *(const uint4*)&Ah[ga];
      *(uint4*)&Asl[row][col] = *(const uint4*)&Al[ga];
      *(uint4*)&Bsh[row][col] = *(const uint4*)&Bh[gb];
      *(uint4*)&Bsl[row][col] = *(const uint4*)&Bl[gb];
    }
    __syncthreads();
    for (int ks = 0; ks < 2; ++ks) {
      f16x8 afh[4], afl[4], bfh[4], bfl[4];
      for (int mt = 0; mt < 4; ++mt) {
        afh[mt] = *(const f16x8*)&Ash[wm + mt * 16 + l16][ks * 32 + quad * 8];
        afl[mt] = *(const f16x8*)&Asl[wm + mt * 16 + l16][ks * 32 + quad * 8];
      }
      for (int nt = 0; nt < 4; ++nt) {
        bfh[nt] = *(const f16x8*)&Bsh[wn + nt * 16 + l16][ks * 32 + quad * 8];
        bfl[nt] = *(const f16x8*)&Bsl[wn + nt * 16 + l16][ks * 32 + quad * 8];
      }
      for (int mt = 0; mt < 4; ++mt)
        for (int nt = 0; nt < 4; ++nt) {
          acc_hh[mt][nt] = __builtin_amdgcn_mfma_f32_16x16x32_f16(afh[mt], bfh[nt], acc_hh[mt][nt], 0, 0, 0);
          acc_cr[mt][nt] = __builtin_amdgcn_mfma_f32_16x16x32_f16(afh[mt], bfl[nt], acc_cr[mt][nt], 0, 0, 0);
          acc_cr[mt][nt] = __builtin_amdgcn_mfma_f32_16x16x32_f16(afl[mt], bfh[nt], acc_cr[mt][nt], 0, 0, 0);
        }
    }
    __syncthreads();
  }

  for (int mt = 0; mt < 4; ++mt)
    for (int nt = 0; nt < 4; ++nt)
      for (int r = 0; r < 4; ++r) {
        int m = bm + wm + mt * 16 + quad * 4 + r;
        int n = bn + wn + nt * 16 + l16;
        C[(size_t)m * N + n] = (OutT)(acc_hh[mt][nt][r] + acc_cr[mt][nt][r] * INV_LOSCALE);
      }
}

// ---------------------------------------------------------------------------
// V16 [B,L,H,D] (viewed [BL][E]) -> Vt_g [B][H*D][L]  (global transpose,
// LDS-bounced, coalesced both sides)
// ---------------------------------------------------------------------------
__global__ __launch_bounds__(256) void transpose_v(const _Float16* __restrict__ V,
                                                   _Float16* __restrict__ Vt) {
  __shared__ _Float16 T[64][72];
  const int bl0 = blockIdx.x * 64, n0 = blockIdx.y * 64;
  const int tid = threadIdx.x;
  for (int c = 0; c < 2; ++c) {
    int chunk = tid + c * 256;
    int r = chunk >> 3, cc = (chunk & 7) * 8;
    *(uint4*)&T[r][cc] = *(const uint4*)&V[(size_t)(bl0 + r) * Ee + n0 + cc];
  }
  __syncthreads();
  const int b = bl0 >> 11;          // bl0 / L
  const int k0 = bl0 & (Ll - 1);
  for (int c = 0; c < 2; ++c) {
    int chunk = tid + c * 256;
    int nr = chunk >> 3, kc = (chunk & 7) * 8;
    _Float16 tmp[8];
    for (int j = 0; j < 8; ++j) tmp[j] = T[kc + j][nr];
    *(uint4*)&Vt[((size_t)b * Ee + n0 + nr) * Ll + k0 + kc] = *(uint4*)tmp;
  }
}

// ---------------------------------------------------------------------------
// Fused RMSNorm (fp32) + rotary + outmul -> split fp16 (hi, lo*1024)
// ---------------------------------------------------------------------------
__global__ __launch_bounds__(256) void rmsrope(const float* __restrict__ raw,
                                               const float* __restrict__ scale,
                                               const float* __restrict__ rope,
                                               _Float16* __restrict__ outh,
                                               _Float16* __restrict__ outl, float outmul) {
  int row = blockIdx.x * 4 + (threadIdx.x >> 6);
  int t = threadIdx.x & 63;
  float2 x = *(const float2*)&raw[(size_t)row * Dd + 2 * t];
  float ss = x.x * x.x + x.y * x.y;
  for (int off = 1; off < 64; off <<= 1) ss += __shfl_xor(ss, off);
  float inv = rsqrtf(ss * (1.0f / Dd) + 1e-6f);
  float2 sc = *(const float2*)&scale[2 * t];
  float y0 = x.x * inv * sc.x;
  float y1 = x.y * inv * sc.y;
  int bl = row >> 4;  // row / H
  float2 cs = *(const float2*)&rope[(size_t)bl * Dd + 2 * t];
  float r0 = (y0 * cs.x - y1 * cs.y) * outmul;
  float r1 = (y1 * cs.x + y0 * cs.y) * outmul;
  _Float16 h[2] = {(_Float16)r0, (_Float16)r1};
  _Float16 l[2] = {(_Float16)((r0 - (float)h[0]) * LOSCALE),
                   (_Float16)((r1 - (float)h[1]) * LOSCALE)};
  *(uint*)&outh[(size_t)row * Dd + 2 * t] = *(uint*)h;
  *(uint*)&outl[(size_t)row * Dd + 2 * t] = *(uint*)l;
}

// ---------------------------------------------------------------------------
// Flash attention, 128 q-rows/block (4 waves x 32 rows, 2 A-tiles each).
// Split-fp16 QK^T (3 MFMAs); Q fragments resident in registers; K hi/lo and
// V^T staged in padded LDS (conflict-free); P via wave-private LDS.
// ---------------------------------------------------------------------------
__global__ __launch_bounds__(256, 2) void attn(const _Float16* __restrict__ Qh_,
                                               const _Float16* __restrict__ Ql_,
                                               const _Float16* __restrict__ Kh_,
                                               const _Float16* __restrict__ Kl_,
                                               const _Float16* __restrict__ Vt_g,
                                               const float* __restrict__ bias,
                                               _Float16* __restrict__ O) {
  __shared__ _Float16 Ksh[64][136];
  __shared__ _Float16 Ksl[64][136];
  __shared__ _Float16 Vts[128][72];
  __shared__ _Float16 Ps[128][72];

  const int tid = threadIdx.x;
  const int wave = tid >> 6, lane = tid & 63;
  const int quad = lane >> 4, l16 = lane & 15;
  const int q0 = blockIdx.x * 128;
  const int h = blockIdx.y, b = blockIdx.z;

  // Q fragments resident (A-layout): tile t rows q0+wave*32+t*16+l16
  f16x8 aqh[2][4], aql[2][4];
  for (int t = 0; t < 2; ++t) {
    size_t qrow = (((size_t)b * Ll + q0 + wave * 32 + t * 16 + l16) * Hh + h) * Dd;
    for (int ks = 0; ks < 4; ++ks) {
      aqh[t][ks] = *(const f16x8*)&Qh_[qrow + ks * 32 + quad * 8];
      aql[t][ks] = *(const f16x8*)&Ql_[qrow + ks * 32 + quad * 8];
    }
  }
  const _Float16* Vbase = Vt_g + ((size_t)b * Ee + h * Dd) * Ll;

  f32x4 o_acc[2][8] = {};
  float m_r[2][4], l_r[2][4];
  for (int t = 0; t < 2; ++t)
    for (int r = 0; r < 4; ++r) { m_r[t][r] = -1e30f; l_r[t][r] = 0.f; }

  for (int kt = 0; kt < Ll / 64; ++kt) {
    const int k0 = kt * 64;
    for (int c = 0; c < 4; ++c) {
      int chunk = tid + c * 256;
      int row = chunk >> 4, col = (chunk & 15) * 8;
      size_t g = (((size_t)b * Ll + k0 + row) * Hh + h) * Dd + col;
      *(uint4*)&Ksh[row][col] = *(const uint4*)&Kh_[g];
      *(uint4*)&Ksl[row][col] = *(const uint4*)&Kl_[g];
      int d = chunk >> 3, kc = (chunk & 7) * 8;
      *(uint4*)&Vts[d][kc] = *(const uint4*)&Vbase[(size_t)d * Ll + k0 + kc];
    }
    __syncthreads();

    // S = Q@K^T (hi/lo): 2 q-tiles x 4 k-col-tiles
    f32x4 s_hh[2][4] = {}, s_cr[2][4] = {};
    for (int ks = 0; ks < 4; ++ks)
      for (int nt = 0; nt < 4; ++nt) {
        f16x8 bkh = *(const f16x8*)&Ksh[nt * 16 + l16][ks * 32 + quad * 8];
        f16x8 bkl = *(const f16x8*)&Ksl[nt * 16 + l16][ks * 32 + quad * 8];
        for (int t = 0; t < 2; ++t) {
          s_hh[t][nt] = __builtin_amdgcn_mfma_f32_16x16x32_f16(aqh[t][ks], bkh, s_hh[t][nt], 0, 0, 0);
          s_cr[t][nt] = __builtin_amdgcn_mfma_f32_16x16x32_f16(aqh[t][ks], bkl, s_cr[t][nt], 0, 0, 0);
          s_cr[t][nt] = __builtin_amdgcn_mfma_f32_16x16x32_f16(aql[t][ks], bkh, s_cr[t][nt], 0, 0, 0);
        }
      }

    for (int t = 0; t < 2; ++t) {
      f32x4 sv[4];
      for (int nt = 0; nt < 4; ++nt)
        for (int r = 0; r < 4; ++r) {
          int gq = q0 + wave * 32 + t * 16 + quad * 4 + r;
          int gk = k0 + nt * 16 + l16;
          sv[nt][r] = s_hh[t][nt][r] + s_cr[t][nt][r] * INV_LOSCALE +
                      bias[((size_t)b * Ll + gq) * Ll + gk];
        }
      float alpha[4];
      for (int r = 0; r < 4; ++r) {
        float x = fmaxf(fmaxf(sv[0][r], sv[1][r]), fmaxf(sv[2][r], sv[3][r]));
        for (int off = 1; off < 16; off <<= 1) x = fmaxf(x, __shfl_xor(x, off));
        float mn = fmaxf(m_r[t][r], x);
        alpha[r] = __expf(m_r[t][r] - mn);
        m_r[t][r] = mn;
      }
      for (int r = 0; r < 4; ++r) {
        float sum = 0.f;
        for (int nt = 0; nt < 4; ++nt) {
          float p = __expf(sv[nt][r] - m_r[t][r]);
          sum += p;
          Ps[wave * 32 + t * 16 + quad * 4 + r][nt * 16 + l16] = (_Float16)p;
        }
        for (int off = 1; off < 16; off <<= 1) sum += __shfl_xor(sum, off);
        l_r[t][r] = l_r[t][r] * alpha[r] + sum;
      }
      for (int ot = 0; ot < 8; ++ot)
        for (int r = 0; r < 4; ++r) o_acc[t][ot][r] *= alpha[r];
    }

    // O += P @ V   (Ps wave-private round-trip; Vts shared)
    for (int ks = 0; ks < 2; ++ks) {
      f16x8 ap[2];
      for (int t = 0; t < 2; ++t)
        ap[t] = *(const f16x8*)&Ps[wave * 32 + t * 16 + l16][ks * 32 + quad * 8];
      for (int ot = 0; ot < 8; ++ot) {
        f16x8 bv = *(const f16x8*)&Vts[ot * 16 + l16][ks * 32 + quad * 8];
        for (int t = 0; t < 2; ++t)
          o_acc[t][ot] = __builtin_amdgcn_mfma_f32_16x16x32_f16(ap[t], bv, o_acc[t][ot], 0, 0, 0);
      }
    }
    __syncthreads();
  }

  for (int t = 0; t < 2; ++t)
    for (int ot = 0; ot < 8; ++ot)
      for (int r = 0; r < 4; ++r) {
        int m = q0 + wave * 32 + t * 16 + quad * 4 + r;
        O[(((size_t)b * Ll + m) * Hh + h) * Dd + ot * 16 + l16] =
            (_Float16)(o_acc[t][ot][r] / l_r[t][r]);
      }
}

// ---------------------------------------------------------------------------
extern "C" void kernel_launch(void* const* d_in, const int* in_sizes, int n_in,
                              void* d_out, int out_size, void* d_ws, size_t ws_size,
                              hipStream_t stream) {
  const float* inputs_q  = (const float*)d_in[0];
  const float* inputs_kv = (const float*)d_in[1];
  const float* bias      = (const float*)d_in[2];
  const float* rope_q    = (const float*)d_in[3];
  const float* rope_k    = (const float*)d_in[4];
  const float* Wq        = (const float*)d_in[5];
  const float* Wk        = (const float*)d_in[6];
  const float* Wv        = (const float*)d_in[7];
  const float* Wo        = (const float*)d_in[8];
  const float* q_scale   = (const float*)d_in[9];
  const float* k_scale   = (const float*)d_in[10];
  float* out = (float*)d_out;

  char* ws = (char*)d_ws;
  size_t o = 0;
  auto alloc = [&](size_t bytes) {
    char* p = ws + o;
    o += (bytes + 255) & ~(size_t)255;
    return p;
  };
  const size_t szX16 = (size_t)BL * Ee * 2;   // 16 MB
  const size_t szW16 = (size_t)Ee * Ee * 2;   // 8 MB
  _Float16* Xq_hi  = (_Float16*)alloc(szX16);
  _Float16* Xq_lo  = (_Float16*)alloc(szX16);
  _Float16* Xkv_hi = (_Float16*)alloc(szX16);
  _Float16* Xkv_lo = (_Float16*)alloc(szX16);
  _Float16* Wq_hi  = (_Float16*)alloc(szW16);
  _Float16* Wq_lo  = (_Float16*)alloc(szW16);
  _Float16* Wk_hi  = (_Float16*)alloc(szW16);
  _Float16* Wk_lo  = (_Float16*)alloc(szW16);
  _Float16* Wv_hi  = (_Float16*)alloc(szW16);
  _Float16* Wo_hi  = (_Float16*)alloc(szW16);
  float* Qraw = (float*)alloc((size_t)BL * Ee * 4);   // 32 MB
  float* Kraw = (float*)alloc((size_t)BL * Ee * 4);   // 32 MB
  _Float16* V16 = (_Float16*)alloc(szX16);
  // aliases (stream-ordered reuse; lifetimes disjoint)
  _Float16* Q16h = Xq_hi;            // Xq dead after Q projection
  _Float16* Q16l = Xq_lo;
  _Float16* K16h = Xkv_hi;           // Xkv dead after K/V projections
  _Float16* K16l = Xkv_lo;
  _Float16* X16  = (_Float16*)Qraw;  // Qraw dead after rmsrope
  _Float16* Vt_g = Wq_hi;            // Wq (hi+lo, 16MB contig) dead after Q proj

  const int nX4 = BL * Ee / 4;
  const int nW4 = Ee * Ee / 4;
  cvt_split<<<nX4 / 256, 256, 0, stream>>>(inputs_q, Xq_hi, Xq_lo, nX4);
  cvt_split<<<nX4 / 256, 256, 0, stream>>>(inputs_kv, Xkv_hi, Xkv_lo, nX4);
  cvt_split<<<nW4 / 256, 256, 0, stream>>>(Wq, Wq_hi, Wq_lo, nW4);
  cvt_split<<<nW4 / 256, 256, 0, stream>>>(Wk, Wk_hi, Wk_lo, nW4);
  cvt_f32_f16<<<nW4 / 256, 256, 0, stream>>>(Wv, Wv_hi, nW4);
  cvt_f32_f16<<<nW4 / 256, 256, 0, stream>>>(Wo, Wo_hi, nW4);

  dim3 gblk(Ee / 128, BL / 128);  // (16, 32)
  gemm_bt_split<float><<<gblk, 256, 0, stream>>>(Xq_hi, Xq_lo, Wq_hi, Wq_lo, Qraw, BL, Ee, Ee);
  gemm_bt_split<float><<<gblk, 256, 0, stream>>>(Xkv_hi, Xkv_lo, Wk_hi, Wk_lo, Kraw, BL, Ee, Ee);
  gemm_bt<_Float16><<<gblk, 256, 0, stream>>>(Xkv_hi, Wv_hi, V16, BL, Ee, Ee);

  transpose_v<<<dim3(BL / 64, Ee / 64), 256, 0, stream>>>(V16, Vt_g);

  rmsrope<<<BL * Hh / 4, 256, 0, stream>>>(Qraw, q_scale, rope_q, Q16h, Q16l, sqrtf((float)Dd));
  rmsrope<<<BL * Hh / 4, 256, 0, stream>>>(Kraw, k_scale, rope_k, K16h, K16l, 1.0f);

  attn<<<dim3(Ll / 128, Hh, Bb), 256, 0, stream>>>(Q16h, Q16l, K16h, K16l, Vt_g, bias, X16);

  gemm_bt<float><<<gblk, 256, 0, stream>>>(X16, Wo_hi, out, BL, Ee, Ee);
}

// Round 4
// 814.148 us; speedup vs baseline: 1.8999x; 1.1495x over previous
//
#include <hip/hip_runtime.h>

// Problem constants
#define Bb 2
#define Ll 2048
#define Ee 2048
#define Hh 16
#define Dd 128
#define BL (Bb * Ll)   // 4096
#define LOSCALE 1024.0f
#define INV_LOSCALE (1.0f / 1024.0f)

typedef float f32x4 __attribute__((ext_vector_type(4)));
typedef _Float16 f16x8 __attribute__((ext_vector_type(8)));

// Async global->LDS, 16B per lane. Dest = wave-uniform base + lane*16.
// Source is PER-LANE, so XOR swizzles are applied on the source address.
__device__ __forceinline__ void gld_lds16(const void* g, void* l) {
  __builtin_amdgcn_global_load_lds((const __attribute__((address_space(1))) void*)g,
                                   (__attribute__((address_space(3))) void*)l, 16, 0, 0);
}

// ---------------------------------------------------------------------------
// f32 -> f16 plain convert (4 elems / thread)
// ---------------------------------------------------------------------------
__global__ __launch_bounds__(256) void cvt_f32_f16(const float* __restrict__ in,
                                                   _Float16* __restrict__ out, int n4) {
  int i = blockIdx.x * 256 + threadIdx.x;
  if (i < n4) {
    float4 f = ((const float4*)in)[i];
    _Float16 o[4] = {(_Float16)f.x, (_Float16)f.y, (_Float16)f.z, (_Float16)f.w};
    ((uint2*)out)[i] = *(uint2*)o;
  }
}

// ---------------------------------------------------------------------------
// f32 -> split fp16: hi = rn(x), lo = rn((x - hi) * 1024)  (eps^2 precision)
// ---------------------------------------------------------------------------
__global__ __launch_bounds__(256) void cvt_split(const float* __restrict__ in,
                                                 _Float16* __restrict__ hi,
                                                 _Float16* __restrict__ lo, int n4) {
  int i = blockIdx.x * 256 + threadIdx.x;
  if (i < n4) {
    float4 f = ((const float4*)in)[i];
    float fa[4] = {f.x, f.y, f.z, f.w};
    _Float16 h[4], l[4];
    for (int j = 0; j < 4; ++j) {
      h[j] = (_Float16)fa[j];
      l[j] = (_Float16)((fa[j] - (float)h[j]) * LOSCALE);
    }
    ((uint2*)hi)[i] = *(uint2*)h;
    ((uint2*)lo)[i] = *(uint2*)l;
  }
}

// ---------------------------------------------------------------------------
// Plain GEMM:  C[M,N] = A[M,K] @ Bw[N,K]^T.
// global_load_lds(16B) staging, XOR-swizzled chunks (8-half chunks, c^row&7)
// -> conflict-free ds_read_b128 without padding.
// ---------------------------------------------------------------------------
template <typename OutT>
__global__ __launch_bounds__(256, 2) void gemm_bt(const _Float16* __restrict__ A,
                                                  const _Float16* __restrict__ Bw,
                                                  OutT* __restrict__ C, int M, int N, int K) {
  __shared__ _Float16 As[128 * 64];
  __shared__ _Float16 Bs[128 * 64];
  const int tid = threadIdx.x;
  const int wave = tid >> 6, lane = tid & 63;
  const int quad = lane >> 4, l16 = lane & 15;
  const int lrow = lane >> 3, lch = lane & 7;
  const int scol = (lch ^ lrow) * 8;  // swizzled source col (halfs)
  const int bm = blockIdx.y * 128, bn = blockIdx.x * 128;
  const int wm = (wave >> 1) * 64, wn = (wave & 1) * 64;

  f32x4 acc[4][4] = {};

  for (int k0 = 0; k0 < K; k0 += 64) {
    for (int i = 0; i < 4; ++i) {
      int br = wave * 32 + i * 8;
      gld_lds16(&A[(size_t)(bm + br + lrow) * K + k0 + scol], &As[br * 64]);
      gld_lds16(&Bw[(size_t)(bn + br + lrow) * K + k0 + scol], &Bs[br * 64]);
    }
    __syncthreads();
    for (int ks = 0; ks < 2; ++ks) {
      f16x8 af[4], bf[4];
      for (int mt = 0; mt < 4; ++mt)
        af[mt] = *(const f16x8*)&As[(wm + mt * 16 + l16) * 64 +
                                    (((ks * 4 + quad) ^ (l16 & 7)) * 8)];
      for (int nt = 0; nt < 4; ++nt)
        bf[nt] = *(const f16x8*)&Bs[(wn + nt * 16 + l16) * 64 +
                                    (((ks * 4 + quad) ^ (l16 & 7)) * 8)];
      for (int mt = 0; mt < 4; ++mt)
        for (int nt = 0; nt < 4; ++nt)
          acc[mt][nt] = __builtin_amdgcn_mfma_f32_16x16x32_f16(af[mt], bf[nt], acc[mt][nt], 0, 0, 0);
    }
    __syncthreads();
  }

  for (int mt = 0; mt < 4; ++mt)
    for (int nt = 0; nt < 4; ++nt)
      for (int r = 0; r < 4; ++r) {
        int m = bm + wm + mt * 16 + quad * 4 + r;
        int n = bn + wn + nt * 16 + l16;
        C[(size_t)m * N + n] = (OutT)acc[mt][nt][r];
      }
}

// ---------------------------------------------------------------------------
// Fused split GEMM:  C = Ah@Bh^T + (Ah@Bl^T + Al@Bh^T)/1024
// Same swizzled global_load_lds staging, 4 tiles, 3 MFMAs per fragment pair.
// ---------------------------------------------------------------------------
__global__ __launch_bounds__(256, 2) void gemm_bt_split(
    const _Float16* __restrict__ Ah, const _Float16* __restrict__ Al,
    const _Float16* __restrict__ Bh, const _Float16* __restrict__ Bl,
    float* __restrict__ C, int M, int N, int K) {
  __shared__ _Float16 Ash[128 * 64];
  __shared__ _Float16 Asl[128 * 64];
  __shared__ _Float16 Bsh[128 * 64];
  __shared__ _Float16 Bsl[128 * 64];
  const int tid = threadIdx.x;
  const int wave = tid >> 6, lane = tid & 63;
  const int quad = lane >> 4, l16 = lane & 15;
  const int lrow = lane >> 3, lch = lane & 7;
  const int scol = (lch ^ lrow) * 8;
  const int bm = blockIdx.y * 128, bn = blockIdx.x * 128;
  const int wm = (wave >> 1) * 64, wn = (wave & 1) * 64;

  f32x4 acc_hh[4][4] = {};
  f32x4 acc_cr[4][4] = {};

  for (int k0 = 0; k0 < K; k0 += 64) {
    for (int i = 0; i < 4; ++i) {
      int br = wave * 32 + i * 8;
      size_t ga = (size_t)(bm + br + lrow) * K + k0 + scol;
      size_t gb = (size_t)(bn + br + lrow) * K + k0 + scol;
      gld_lds16(&Ah[ga], &Ash[br * 64]);
      gld_lds16(&Al[ga], &Asl[br * 64]);
      gld_lds16(&Bh[gb], &Bsh[br * 64]);
      gld_lds16(&Bl[gb], &Bsl[br * 64]);
    }
    __syncthreads();
    for (int ks = 0; ks < 2; ++ks) {
      const int sw = ((ks * 4 + quad) ^ (l16 & 7)) * 8;
      f16x8 afh[4], afl[4], bfh[4], bfl[4];
      for (int mt = 0; mt < 4; ++mt) {
        afh[mt] = *(const f16x8*)&Ash[(wm + mt * 16 + l16) * 64 + sw];
        afl[mt] = *(const f16x8*)&Asl[(wm + mt * 16 + l16) * 64 + sw];
      }
      for (int nt = 0; nt < 4; ++nt) {
        bfh[nt] = *(const f16x8*)&Bsh[(wn + nt * 16 + l16) * 64 + sw];
        bfl[nt] = *(const f16x8*)&Bsl[(wn + nt * 16 + l16) * 64 + sw];
      }
      for (int mt = 0; mt < 4; ++mt)
        for (int nt = 0; nt < 4; ++nt) {
          acc_hh[mt][nt] = __builtin_amdgcn_mfma_f32_16x16x32_f16(afh[mt], bfh[nt], acc_hh[mt][nt], 0, 0, 0);
          acc_cr[mt][nt] = __builtin_amdgcn_mfma_f32_16x16x32_f16(afh[mt], bfl[nt], acc_cr[mt][nt], 0, 0, 0);
          acc_cr[mt][nt] = __builtin_amdgcn_mfma_f32_16x16x32_f16(afl[mt], bfh[nt], acc_cr[mt][nt], 0, 0, 0);
        }
    }
    __syncthreads();
  }

  for (int mt = 0; mt < 4; ++mt)
    for (int nt = 0; nt < 4; ++nt)
      for (int r = 0; r < 4; ++r) {
        int m = bm + wm + mt * 16 + quad * 4 + r;
        int n = bn + wn + nt * 16 + l16;
        C[(size_t)m * N + n] = acc_hh[mt][nt][r] + acc_cr[mt][nt][r] * INV_LOSCALE;
      }
}

// ---------------------------------------------------------------------------
// V16 [B,L,H,D] (viewed [BL][E]) -> Vt_g [B][H*D][L]
// ---------------------------------------------------------------------------
__global__ __launch_bounds__(256) void transpose_v(const _Float16* __restrict__ V,
                                                   _Float16* __restrict__ Vt) {
  __shared__ _Float16 T[64][72];
  const int bl0 = blockIdx.x * 64, n0 = blockIdx.y * 64;
  const int tid = threadIdx.x;
  for (int c = 0; c < 2; ++c) {
    int chunk = tid + c * 256;
    int r = chunk >> 3, cc = (chunk & 7) * 8;
    *(uint4*)&T[r][cc] = *(const uint4*)&V[(size_t)(bl0 + r) * Ee + n0 + cc];
  }
  __syncthreads();
  const int b = bl0 >> 11;
  const int k0 = bl0 & (Ll - 1);
  for (int c = 0; c < 2; ++c) {
    int chunk = tid + c * 256;
    int nr = chunk >> 3, kc = (chunk & 7) * 8;
    _Float16 tmp[8];
    for (int j = 0; j < 8; ++j) tmp[j] = T[kc + j][nr];
    *(uint4*)&Vt[((size_t)b * Ee + n0 + nr) * Ll + k0 + kc] = *(uint4*)tmp;
  }
}

// ---------------------------------------------------------------------------
// Fused RMSNorm (fp32) + rotary + outmul -> split fp16 (hi, lo*1024)
// ---------------------------------------------------------------------------
__global__ __launch_bounds__(256) void rmsrope(const float* __restrict__ raw,
                                               const float* __restrict__ scale,
                                               const float* __restrict__ rope,
                                               _Float16* __restrict__ outh,
                                               _Float16* __restrict__ outl, float outmul) {
  int row = blockIdx.x * 4 + (threadIdx.x >> 6);
  int t = threadIdx.x & 63;
  float2 x = *(const float2*)&raw[(size_t)row * Dd + 2 * t];
  float ss = x.x * x.x + x.y * x.y;
  for (int off = 1; off < 64; off <<= 1) ss += __shfl_xor(ss, off);
  float inv = rsqrtf(ss * (1.0f / Dd) + 1e-6f);
  float2 sc = *(const float2*)&scale[2 * t];
  float y0 = x.x * inv * sc.x;
  float y1 = x.y * inv * sc.y;
  int bl = row >> 4;
  float2 cs = *(const float2*)&rope[(size_t)bl * Dd + 2 * t];
  float r0 = (y0 * cs.x - y1 * cs.y) * outmul;
  float r1 = (y1 * cs.x + y0 * cs.y) * outmul;
  _Float16 h[2] = {(_Float16)r0, (_Float16)r1};
  _Float16 l[2] = {(_Float16)((r0 - (float)h[0]) * LOSCALE),
                   (_Float16)((r1 - (float)h[1]) * LOSCALE)};
  *(uint*)&outh[(size_t)row * Dd + 2 * t] = *(uint*)h;
  *(uint*)&outl[(size_t)row * Dd + 2 * t] = *(uint*)l;
}

// ---------------------------------------------------------------------------
// Flash attention, 128 q-rows/block. Grid (H, L/128, B): heads vary fastest
// so co-resident blocks share the same bias slice (L2/L3-hot). Bias is fp16.
// K/V tiles staged via swizzled global_load_lds; Q resident in registers.
// ---------------------------------------------------------------------------
__global__ __launch_bounds__(256, 2) void attn(const _Float16* __restrict__ Qh_,
                                               const _Float16* __restrict__ Ql_,
                                               const _Float16* __restrict__ Kh_,
                                               const _Float16* __restrict__ Kl_,
                                               const _Float16* __restrict__ Vt_g,
                                               const _Float16* __restrict__ bias16,
                                               _Float16* __restrict__ O) {
  __shared__ _Float16 Ksh[64 * 128];   // swizzled
  __shared__ _Float16 Ksl[64 * 128];   // swizzled
  __shared__ _Float16 Vts[128 * 64];   // swizzled, Vt[d][k]
  __shared__ _Float16 Ps[128][72];     // padded (VALU-written)

  const int tid = threadIdx.x;
  const int wave = tid >> 6, lane = tid & 63;
  const int quad = lane >> 4, l16 = lane & 15;
  const int lrow8 = lane >> 3, lch8 = lane & 7;
  const int lrow16 = lane >> 4, lch16 = lane & 15;
  const int h = blockIdx.x;
  const int q0 = blockIdx.y * 128;
  const int b = blockIdx.z;

  f16x8 aqh[2][4], aql[2][4];
  for (int t = 0; t < 2; ++t) {
    size_t qrow = (((size_t)b * Ll + q0 + wave * 32 + t * 16 + l16) * Hh + h) * Dd;
    for (int ks = 0; ks < 4; ++ks) {
      aqh[t][ks] = *(const f16x8*)&Qh_[qrow + ks * 32 + quad * 8];
      aql[t][ks] = *(const f16x8*)&Ql_[qrow + ks * 32 + quad * 8];
    }
  }
  const _Float16* Vbase = Vt_g + ((size_t)b * Ee + h * Dd) * Ll;
  const _Float16* biasb = bias16 + (size_t)b * Ll * Ll;

  f32x4 o_acc[2][8] = {};
  float m_r[2][4], l_r[2][4];
  for (int t = 0; t < 2; ++t)
    for (int r = 0; r < 4; ++r) { m_r[t][r] = -1e30f; l_r[t][r] = 0.f; }

  for (int kt = 0; kt < Ll / 64; ++kt) {
    const int k0 = kt * 64;
    // K tiles: 64 rows x 256B, 4 rows per wave-call, 4 calls/wave
    for (int i = 0; i < 4; ++i) {
      int br = wave * 16 + i * 4;
      int row = br + lrow16;
      int sc = (lch16 ^ (row & 7)) * 8;
      size_t g = (((size_t)b * Ll + k0 + row) * Hh + h) * Dd + sc;
      gld_lds16(&Kh_[g], &Ksh[br * 128]);
      gld_lds16(&Kl_[g], &Ksl[br * 128]);
    }
    // V^T tile: 128 rows x 128B, 8 rows per wave-call, 4 calls/wave
    for (int i = 0; i < 4; ++i) {
      int br = wave * 32 + i * 8;
      int row = br + lrow8;
      int sc = (lch8 ^ (row & 7)) * 8;
      gld_lds16(&Vbase[(size_t)row * Ll + k0 + sc], &Vts[br * 64]);
    }
    __syncthreads();

    // S = Q@K^T (hi/lo)
    f32x4 s_hh[2][4] = {}, s_cr[2][4] = {};
    for (int ks = 0; ks < 4; ++ks) {
      const int sw = ((ks * 4 + quad) ^ (l16 & 7)) * 8;
      for (int nt = 0; nt < 4; ++nt) {
        f16x8 bkh = *(const f16x8*)&Ksh[(nt * 16 + l16) * 128 + sw];
        f16x8 bkl = *(const f16x8*)&Ksl[(nt * 16 + l16) * 128 + sw];
        for (int t = 0; t < 2; ++t) {
          s_hh[t][nt] = __builtin_amdgcn_mfma_f32_16x16x32_f16(aqh[t][ks], bkh, s_hh[t][nt], 0, 0, 0);
          s_cr[t][nt] = __builtin_amdgcn_mfma_f32_16x16x32_f16(aqh[t][ks], bkl, s_cr[t][nt], 0, 0, 0);
          s_cr[t][nt] = __builtin_amdgcn_mfma_f32_16x16x32_f16(aql[t][ks], bkh, s_cr[t][nt], 0, 0, 0);
        }
      }
    }

    for (int t = 0; t < 2; ++t) {
      f32x4 sv[4];
      for (int nt = 0; nt < 4; ++nt)
        for (int r = 0; r < 4; ++r) {
          int gq = q0 + wave * 32 + t * 16 + quad * 4 + r;
          int gk = k0 + nt * 16 + l16;
          sv[nt][r] = s_hh[t][nt][r] + s_cr[t][nt][r] * INV_LOSCALE +
                      (float)biasb[(size_t)gq * Ll + gk];
        }
      float alpha[4];
      for (int r = 0; r < 4; ++r) {
        float x = fmaxf(fmaxf(sv[0][r], sv[1][r]), fmaxf(sv[2][r], sv[3][r]));
        for (int off = 1; off < 16; off <<= 1) x = fmaxf(x, __shfl_xor(x, off));
        float mn = fmaxf(m_r[t][r], x);
        alpha[r] = __expf(m_r[t][r] - mn);
        m_r[t][r] = mn;
      }
      for (int r = 0; r < 4; ++r) {
        float sum = 0.f;
        for (int nt = 0; nt < 4; ++nt) {
          float p = __expf(sv[nt][r] - m_r[t][r]);
          sum += p;
          Ps[wave * 32 + t * 16 + quad * 4 + r][nt * 16 + l16] = (_Float16)p;
        }
        for (int off = 1; off < 16; off <<= 1) sum += __shfl_xor(sum, off);
        l_r[t][r] = l_r[t][r] * alpha[r] + sum;
      }
      for (int ot = 0; ot < 8; ++ot)
        for (int r = 0; r < 4; ++r) o_acc[t][ot][r] *= alpha[r];
    }

    // O += P @ V
    for (int ks = 0; ks < 2; ++ks) {
      const int sw = ((ks * 4 + quad) ^ (l16 & 7)) * 8;
      f16x8 ap[2];
      for (int t = 0; t < 2; ++t)
        ap[t] = *(const f16x8*)&Ps[wave * 32 + t * 16 + l16][ks * 32 + quad * 8];
      for (int ot = 0; ot < 8; ++ot) {
        f16x8 bv = *(const f16x8*)&Vts[(ot * 16 + l16) * 64 + sw];
        for (int t = 0; t < 2; ++t)
          o_acc[t][ot] = __builtin_amdgcn_mfma_f32_16x16x32_f16(ap[t], bv, o_acc[t][ot], 0, 0, 0);
      }
    }
    __syncthreads();
  }

  for (int t = 0; t < 2; ++t)
    for (int ot = 0; ot < 8; ++ot)
      for (int r = 0; r < 4; ++r) {
        int m = q0 + wave * 32 + t * 16 + quad * 4 + r;
        O[(((size_t)b * Ll + m) * Hh + h) * Dd + ot * 16 + l16] =
            (_Float16)(o_acc[t][ot][r] / l_r[t][r]);
      }
}

// ---------------------------------------------------------------------------
extern "C" void kernel_launch(void* const* d_in, const int* in_sizes, int n_in,
                              void* d_out, int out_size, void* d_ws, size_t ws_size,
                              hipStream_t stream) {
  const float* inputs_q  = (const float*)d_in[0];
  const float* inputs_kv = (const float*)d_in[1];
  const float* bias      = (const float*)d_in[2];
  const float* rope_q    = (const float*)d_in[3];
  const float* rope_k    = (const float*)d_in[4];
  const float* Wq        = (const float*)d_in[5];
  const float* Wk        = (const float*)d_in[6];
  const float* Wv        = (const float*)d_in[7];
  const float* Wo        = (const float*)d_in[8];
  const float* q_scale   = (const float*)d_in[9];
  const float* k_scale   = (const float*)d_in[10];
  float* out = (float*)d_out;

  char* ws = (char*)d_ws;
  size_t o = 0;
  auto alloc = [&](size_t bytes) {
    char* p = ws + o;
    o += (bytes + 255) & ~(size_t)255;
    return p;
  };
  const size_t szX16 = (size_t)BL * Ee * 2;   // 16 MB
  const size_t szW16 = (size_t)Ee * Ee * 2;   // 8 MB
  _Float16* Xq_hi  = (_Float16*)alloc(szX16);
  _Float16* Xq_lo  = (_Float16*)alloc(szX16);
  _Float16* Xkv_hi = (_Float16*)alloc(szX16);
  _Float16* Xkv_lo = (_Float16*)alloc(szX16);
  _Float16* Wq_hi  = (_Float16*)alloc(szW16);
  _Float16* Wq_lo  = (_Float16*)alloc(szW16);
  _Float16* Wk_hi  = (_Float16*)alloc(szW16);
  _Float16* Wk_lo  = (_Float16*)alloc(szW16);
  _Float16* Wv_hi  = (_Float16*)alloc(szW16);
  _Float16* Wo_hi  = (_Float16*)alloc(szW16);
  float* Qraw = (float*)alloc((size_t)BL * Ee * 4);   // 32 MB
  float* Kraw = (float*)alloc((size_t)BL * Ee * 4);   // 32 MB
  _Float16* V16 = (_Float16*)alloc(szX16);
  // aliases (stream-ordered reuse; lifetimes disjoint)
  _Float16* Q16h   = Xq_hi;            // Xq dead after Q projection
  _Float16* Q16l   = Xq_lo;
  _Float16* K16h   = Xkv_hi;           // Xkv dead after K/V projections
  _Float16* K16l   = Xkv_lo;
  _Float16* X16    = (_Float16*)Qraw;  // Qraw dead after rmsrope(Q)
  _Float16* Vt_g   = Wq_hi;            // Wq hi+lo (16MB contig) dead after Q proj
  _Float16* bias16 = (_Float16*)Kraw;  // Kraw dead after rmsrope(K); 16.8MB <= 32MB

  const int nX4 = BL * Ee / 4;
  const int nW4 = Ee * Ee / 4;
  const int nB4 = Bb * Ll * Ll / 4;   // 2,097,152
  cvt_split<<<nX4 / 256, 256, 0, stream>>>(inputs_q, Xq_hi, Xq_lo, nX4);
  cvt_split<<<nX4 / 256, 256, 0, stream>>>(inputs_kv, Xkv_hi, Xkv_lo, nX4);
  cvt_split<<<nW4 / 256, 256, 0, stream>>>(Wq, Wq_hi, Wq_lo, nW4);
  cvt_split<<<nW4 / 256, 256, 0, stream>>>(Wk, Wk_hi, Wk_lo, nW4);
  cvt_f32_f16<<<nW4 / 256, 256, 0, stream>>>(Wv, Wv_hi, nW4);
  cvt_f32_f16<<<nW4 / 256, 256, 0, stream>>>(Wo, Wo_hi, nW4);

  dim3 gblk(Ee / 128, BL / 128);  // (16, 32)
  gemm_bt_split<<<gblk, 256, 0, stream>>>(Xq_hi, Xq_lo, Wq_hi, Wq_lo, Qraw, BL, Ee, Ee);
  gemm_bt_split<<<gblk, 256, 0, stream>>>(Xkv_hi, Xkv_lo, Wk_hi, Wk_lo, Kraw, BL, Ee, Ee);
  gemm_bt<_Float16><<<gblk, 256, 0, stream>>>(Xkv_hi, Wv_hi, V16, BL, Ee, Ee);

  transpose_v<<<dim3(BL / 64, Ee / 64), 256, 0, stream>>>(V16, Vt_g);

  rmsrope<<<BL * Hh / 4, 256, 0, stream>>>(Qraw, q_scale, rope_q, Q16h, Q16l, sqrtf((float)Dd));
  rmsrope<<<BL * Hh / 4, 256, 0, stream>>>(Kraw, k_scale, rope_k, K16h, K16l, 1.0f);

  // bias -> fp16 (into Kraw region, now dead)
  cvt_f32_f16<<<nB4 / 256, 256, 0, stream>>>(bias, bias16, nB4);

  attn<<<dim3(Hh, Ll / 128, Bb), 256, 0, stream>>>(Q16h, Q16l, K16h, K16l, Vt_g, bias16, X16);

  gemm_bt<float><<<gblk, 256, 0, stream>>>(X16, Wo_hi, out, BL, Ee, Ee);
}

// Round 5
// 779.805 us; speedup vs baseline: 1.9836x; 1.0440x over previous
//
#include <hip/hip_runtime.h>

// Problem constants
#define Bb 2
#define Ll 2048
#define Ee 2048
#define Hh 16
#define Dd 128
#define BL (Bb * Ll)   // 4096
#define LOSCALE 1024.0f
#define INV_LOSCALE (1.0f / 1024.0f)

typedef float f32x4 __attribute__((ext_vector_type(4)));
typedef _Float16 f16x8 __attribute__((ext_vector_type(8)));

// Async global->LDS, 16B per lane. Dest = wave-uniform base + lane*16.
// Source is PER-LANE, so XOR swizzles are applied on the source address.
__device__ __forceinline__ void gld_lds16(const void* g, void* l) {
  __builtin_amdgcn_global_load_lds((const __attribute__((address_space(1))) void*)g,
                                   (__attribute__((address_space(3))) void*)l, 16, 0, 0);
}

// ---------------------------------------------------------------------------
// f32 -> f16 plain convert (4 elems / thread)
// ---------------------------------------------------------------------------
__global__ __launch_bounds__(256) void cvt_f32_f16(const float* __restrict__ in,
                                                   _Float16* __restrict__ out, int n4) {
  int i = blockIdx.x * 256 + threadIdx.x;
  if (i < n4) {
    float4 f = ((const float4*)in)[i];
    _Float16 o[4] = {(_Float16)f.x, (_Float16)f.y, (_Float16)f.z, (_Float16)f.w};
    ((uint2*)out)[i] = *(uint2*)o;
  }
}

// ---------------------------------------------------------------------------
// f32 -> split fp16: hi = rn(x), lo = rn((x - hi) * 1024)  (eps^2 precision)
// ---------------------------------------------------------------------------
__global__ __launch_bounds__(256) void cvt_split(const float* __restrict__ in,
                                                 _Float16* __restrict__ hi,
                                                 _Float16* __restrict__ lo, int n4) {
  int i = blockIdx.x * 256 + threadIdx.x;
  if (i < n4) {
    float4 f = ((const float4*)in)[i];
    float fa[4] = {f.x, f.y, f.z, f.w};
    _Float16 h[4], l[4];
    for (int j = 0; j < 4; ++j) {
      h[j] = (_Float16)fa[j];
      l[j] = (_Float16)((fa[j] - (float)h[j]) * LOSCALE);
    }
    ((uint2*)hi)[i] = *(uint2*)h;
    ((uint2*)lo)[i] = *(uint2*)l;
  }
}

// ---------------------------------------------------------------------------
// Plain GEMM:  C[M,N] = A[M,K] @ Bw[N,K]^T.
// global_load_lds(16B) staging, XOR-swizzled chunks -> conflict-free b128.
// ---------------------------------------------------------------------------
template <typename OutT>
__global__ __launch_bounds__(256, 2) void gemm_bt(const _Float16* __restrict__ A,
                                                  const _Float16* __restrict__ Bw,
                                                  OutT* __restrict__ C, int M, int N, int K) {
  __shared__ _Float16 As[128 * 64];
  __shared__ _Float16 Bs[128 * 64];
  const int tid = threadIdx.x;
  const int wave = tid >> 6, lane = tid & 63;
  const int quad = lane >> 4, l16 = lane & 15;
  const int lrow = lane >> 3, lch = lane & 7;
  const int scol = (lch ^ lrow) * 8;  // swizzled source col (halfs)
  const int bm = blockIdx.y * 128, bn = blockIdx.x * 128;
  const int wm = (wave >> 1) * 64, wn = (wave & 1) * 64;

  f32x4 acc[4][4] = {};

  for (int k0 = 0; k0 < K; k0 += 64) {
    for (int i = 0; i < 4; ++i) {
      int br = wave * 32 + i * 8;
      gld_lds16(&A[(size_t)(bm + br + lrow) * K + k0 + scol], &As[br * 64]);
      gld_lds16(&Bw[(size_t)(bn + br + lrow) * K + k0 + scol], &Bs[br * 64]);
    }
    __syncthreads();
    for (int ks = 0; ks < 2; ++ks) {
      f16x8 af[4], bf[4];
      for (int mt = 0; mt < 4; ++mt)
        af[mt] = *(const f16x8*)&As[(wm + mt * 16 + l16) * 64 +
                                    (((ks * 4 + quad) ^ (l16 & 7)) * 8)];
      for (int nt = 0; nt < 4; ++nt)
        bf[nt] = *(const f16x8*)&Bs[(wn + nt * 16 + l16) * 64 +
                                    (((ks * 4 + quad) ^ (l16 & 7)) * 8)];
      for (int mt = 0; mt < 4; ++mt)
        for (int nt = 0; nt < 4; ++nt)
          acc[mt][nt] = __builtin_amdgcn_mfma_f32_16x16x32_f16(af[mt], bf[nt], acc[mt][nt], 0, 0, 0);
    }
    __syncthreads();
  }

  for (int mt = 0; mt < 4; ++mt)
    for (int nt = 0; nt < 4; ++nt)
      for (int r = 0; r < 4; ++r) {
        int m = bm + wm + mt * 16 + quad * 4 + r;
        int n = bn + wn + nt * 16 + l16;
        C[(size_t)m * N + n] = (OutT)acc[mt][nt][r];
      }
}

// ---------------------------------------------------------------------------
// Fused split GEMM:  C = Ah@Bh^T + (Ah@Bl^T + Al@Bh^T)/1024
// ---------------------------------------------------------------------------
__global__ __launch_bounds__(256, 2) void gemm_bt_split(
    const _Float16* __restrict__ Ah, const _Float16* __restrict__ Al,
    const _Float16* __restrict__ Bh, const _Float16* __restrict__ Bl,
    float* __restrict__ C, int M, int N, int K) {
  __shared__ _Float16 Ash[128 * 64];
  __shared__ _Float16 Asl[128 * 64];
  __shared__ _Float16 Bsh[128 * 64];
  __shared__ _Float16 Bsl[128 * 64];
  const int tid = threadIdx.x;
  const int wave = tid >> 6, lane = tid & 63;
  const int quad = lane >> 4, l16 = lane & 15;
  const int lrow = lane >> 3, lch = lane & 7;
  const int scol = (lch ^ lrow) * 8;
  const int bm = blockIdx.y * 128, bn = blockIdx.x * 128;
  const int wm = (wave >> 1) * 64, wn = (wave & 1) * 64;

  f32x4 acc_hh[4][4] = {};
  f32x4 acc_cr[4][4] = {};

  for (int k0 = 0; k0 < K; k0 += 64) {
    for (int i = 0; i < 4; ++i) {
      int br = wave * 32 + i * 8;
      size_t ga = (size_t)(bm + br + lrow) * K + k0 + scol;
      size_t gb = (size_t)(bn + br + lrow) * K + k0 + scol;
      gld_lds16(&Ah[ga], &Ash[br * 64]);
      gld_lds16(&Al[ga], &Asl[br * 64]);
      gld_lds16(&Bh[gb], &Bsh[br * 64]);
      gld_lds16(&Bl[gb], &Bsl[br * 64]);
    }
    __syncthreads();
    for (int ks = 0; ks < 2; ++ks) {
      const int sw = ((ks * 4 + quad) ^ (l16 & 7)) * 8;
      f16x8 afh[4], afl[4], bfh[4], bfl[4];
      for (int mt = 0; mt < 4; ++mt) {
        afh[mt] = *(const f16x8*)&Ash[(wm + mt * 16 + l16) * 64 + sw];
        afl[mt] = *(const f16x8*)&Asl[(wm + mt * 16 + l16) * 64 + sw];
      }
      for (int nt = 0; nt < 4; ++nt) {
        bfh[nt] = *(const f16x8*)&Bsh[(wn + nt * 16 + l16) * 64 + sw];
        bfl[nt] = *(const f16x8*)&Bsl[(wn + nt * 16 + l16) * 64 + sw];
      }
      for (int mt = 0; mt < 4; ++mt)
        for (int nt = 0; nt < 4; ++nt) {
          acc_hh[mt][nt] = __builtin_amdgcn_mfma_f32_16x16x32_f16(afh[mt], bfh[nt], acc_hh[mt][nt], 0, 0, 0);
          acc_cr[mt][nt] = __builtin_amdgcn_mfma_f32_16x16x32_f16(afh[mt], bfl[nt], acc_cr[mt][nt], 0, 0, 0);
          acc_cr[mt][nt] = __builtin_amdgcn_mfma_f32_16x16x32_f16(afl[mt], bfh[nt], acc_cr[mt][nt], 0, 0, 0);
        }
    }
    __syncthreads();
  }

  for (int mt = 0; mt < 4; ++mt)
    for (int nt = 0; nt < 4; ++nt)
      for (int r = 0; r < 4; ++r) {
        int m = bm + wm + mt * 16 + quad * 4 + r;
        int n = bn + wn + nt * 16 + l16;
        C[(size_t)m * N + n] = acc_hh[mt][nt][r] + acc_cr[mt][nt][r] * INV_LOSCALE;
      }
}

// ---------------------------------------------------------------------------
// V16 [B,L,H,D] (viewed [BL][E]) -> Vt_g [B][H*D][L]
// ---------------------------------------------------------------------------
__global__ __launch_bounds__(256) void transpose_v(const _Float16* __restrict__ V,
                                                   _Float16* __restrict__ Vt) {
  __shared__ _Float16 T[64][72];
  const int bl0 = blockIdx.x * 64, n0 = blockIdx.y * 64;
  const int tid = threadIdx.x;
  for (int c = 0; c < 2; ++c) {
    int chunk = tid + c * 256;
    int r = chunk >> 3, cc = (chunk & 7) * 8;
    *(uint4*)&T[r][cc] = *(const uint4*)&V[(size_t)(bl0 + r) * Ee + n0 + cc];
  }
  __syncthreads();
  const int b = bl0 >> 11;
  const int k0 = bl0 & (Ll - 1);
  for (int c = 0; c < 2; ++c) {
    int chunk = tid + c * 256;
    int nr = chunk >> 3, kc = (chunk & 7) * 8;
    _Float16 tmp[8];
    for (int j = 0; j < 8; ++j) tmp[j] = T[kc + j][nr];
    *(uint4*)&Vt[((size_t)b * Ee + n0 + nr) * Ll + k0 + kc] = *(uint4*)tmp;
  }
}

// ---------------------------------------------------------------------------
// Fused RMSNorm (fp32) + rotary + outmul -> split fp16 (hi, lo*1024)
// ---------------------------------------------------------------------------
__global__ __launch_bounds__(256) void rmsrope(const float* __restrict__ raw,
                                               const float* __restrict__ scale,
                                               const float* __restrict__ rope,
                                               _Float16* __restrict__ outh,
                                               _Float16* __restrict__ outl, float outmul) {
  int row = blockIdx.x * 4 + (threadIdx.x >> 6);
  int t = threadIdx.x & 63;
  float2 x = *(const float2*)&raw[(size_t)row * Dd + 2 * t];
  float ss = x.x * x.x + x.y * x.y;
  for (int off = 1; off < 64; off <<= 1) ss += __shfl_xor(ss, off);
  float inv = rsqrtf(ss * (1.0f / Dd) + 1e-6f);
  float2 sc = *(const float2*)&scale[2 * t];
  float y0 = x.x * inv * sc.x;
  float y1 = x.y * inv * sc.y;
  int bl = row >> 4;
  float2 cs = *(const float2*)&rope[(size_t)bl * Dd + 2 * t];
  float r0 = (y0 * cs.x - y1 * cs.y) * outmul;
  float r1 = (y1 * cs.x + y0 * cs.y) * outmul;
  _Float16 h[2] = {(_Float16)r0, (_Float16)r1};
  _Float16 l[2] = {(_Float16)((r0 - (float)h[0]) * LOSCALE),
                   (_Float16)((r1 - (float)h[1]) * LOSCALE)};
  *(uint*)&outh[(size_t)row * Dd + 2 * t] = *(uint*)h;
  *(uint*)&outl[(size_t)row * Dd + 2 * t] = *(uint*)l;
}

// ---------------------------------------------------------------------------
// Flash attention, 512 threads = 8 waves, each wave owns 16 q-rows of a
// 128-row q-tile. 16 waves/CU (2 blocks). Bias tile staged via
// global_load_lds into each wave's private slice of the Ps region (consumed
// into sv before the same wave overwrites it with P — program-ordered, no
// extra barrier, no extra LDS). K hi/lo + V^T in swizzled LDS; Q in regs.
// ---------------------------------------------------------------------------
__global__ __launch_bounds__(512, 4) void attn(const _Float16* __restrict__ Qh_,
                                               const _Float16* __restrict__ Ql_,
                                               const _Float16* __restrict__ Kh_,
                                               const _Float16* __restrict__ Kl_,
                                               const _Float16* __restrict__ Vt_g,
                                               const _Float16* __restrict__ bias16,
                                               _Float16* __restrict__ O) {
  __shared__ _Float16 Ksh[64 * 128];   // swizzled
  __shared__ _Float16 Ksl[64 * 128];   // swizzled
  __shared__ _Float16 Vts[128 * 64];   // swizzled, Vt[d][k]
  __shared__ _Float16 Ps[128 * 72];    // P (stride 72) / per-wave bias tiles

  const int tid = threadIdx.x;
  const int wave = tid >> 6, lane = tid & 63;
  const int quad = lane >> 4, l16 = lane & 15;
  const int lrow8 = lane >> 3, lch8 = lane & 7;
  const int lrow16 = lane >> 4, lch16 = lane & 15;
  const int h = blockIdx.x;
  const int q0 = blockIdx.y * 128;
  const int b = blockIdx.z;

  // Q fragments resident (A-layout): wave's rows q0 + wave*16 + l16
  f16x8 aqh[4], aql[4];
  {
    size_t qrow = (((size_t)b * Ll + q0 + wave * 16 + l16) * Hh + h) * Dd;
    for (int ks = 0; ks < 4; ++ks) {
      aqh[ks] = *(const f16x8*)&Qh_[qrow + ks * 32 + quad * 8];
      aql[ks] = *(const f16x8*)&Ql_[qrow + ks * 32 + quad * 8];
    }
  }
  const _Float16* Vbase = Vt_g + ((size_t)b * Ee + h * Dd) * Ll;
  const _Float16* biasb = bias16 + (size_t)b * Ll * Ll;

  f32x4 o_acc[8] = {};
  float m_r[4], l_r[4];
  for (int r = 0; r < 4; ++r) { m_r[r] = -1e30f; l_r[r] = 0.f; }

  for (int kt = 0; kt < Ll / 64; ++kt) {
    const int k0 = kt * 64;
    // K hi/lo: 64 rows x 256B; each wave stages 8 rows (2 calls x 4 rows)
    for (int i = 0; i < 2; ++i) {
      int br = wave * 8 + i * 4;
      int row = br + lrow16;
      int sc = (lch16 ^ (row & 7)) * 8;
      size_t g = (((size_t)b * Ll + k0 + row) * Hh + h) * Dd + sc;
      gld_lds16(&Kh_[g], &Ksh[br * 128]);
      gld_lds16(&Kl_[g], &Ksl[br * 128]);
    }
    // V^T: 128 rows x 128B; each wave stages 16 rows (2 calls x 8 rows)
    for (int i = 0; i < 2; ++i) {
      int br = wave * 16 + i * 8;
      int row = br + lrow8;
      int sc = (lch8 ^ (row & 7)) * 8;
      gld_lds16(&Vbase[(size_t)row * Ll + k0 + sc], &Vts[br * 64]);
    }
    // bias: wave's 16 q-rows x 64 cols fp16 -> flat [16][64] in own Ps slice
    for (int i = 0; i < 2; ++i) {
      int gq = q0 + wave * 16 + i * 8 + lrow8;
      gld_lds16(&biasb[(size_t)gq * Ll + k0 + lch8 * 8], &Ps[wave * 1152 + i * 512]);
    }
    __syncthreads();

    // S = Q@K^T (hi/lo)
    f32x4 s_hh[4] = {}, s_cr[4] = {};
    for (int ks = 0; ks < 4; ++ks) {
      const int sw = ((ks * 4 + quad) ^ (l16 & 7)) * 8;
      for (int nt = 0; nt < 4; ++nt) {
        f16x8 bkh = *(const f16x8*)&Ksh[(nt * 16 + l16) * 128 + sw];
        f16x8 bkl = *(const f16x8*)&Ksl[(nt * 16 + l16) * 128 + sw];
        s_hh[nt] = __builtin_amdgcn_mfma_f32_16x16x32_f16(aqh[ks], bkh, s_hh[nt], 0, 0, 0);
        s_cr[nt] = __builtin_amdgcn_mfma_f32_16x16x32_f16(aqh[ks], bkl, s_cr[nt], 0, 0, 0);
        s_cr[nt] = __builtin_amdgcn_mfma_f32_16x16x32_f16(aql[ks], bkh, s_cr[nt], 0, 0, 0);
      }
    }
    // combine + bias from LDS (all bias reads precede this wave's Ps writes)
    for (int nt = 0; nt < 4; ++nt)
      for (int r = 0; r < 4; ++r)
        s_hh[nt][r] += s_cr[nt][r] * INV_LOSCALE +
                       (float)Ps[wave * 1152 + (quad * 4 + r) * 64 + nt * 16 + l16];

    // online softmax
    float alpha[4];
    for (int r = 0; r < 4; ++r) {
      float x = fmaxf(fmaxf(s_hh[0][r], s_hh[1][r]), fmaxf(s_hh[2][r], s_hh[3][r]));
      for (int off = 1; off < 16; off <<= 1) x = fmaxf(x, __shfl_xor(x, off));
      float mn = fmaxf(m_r[r], x);
      alpha[r] = __expf(m_r[r] - mn);
      m_r[r] = mn;
    }
    for (int r = 0; r < 4; ++r) {
      float sum = 0.f;
      for (int nt = 0; nt < 4; ++nt) {
        float p = __expf(s_hh[nt][r] - m_r[r]);
        sum += p;
        Ps[(wave * 16 + quad * 4 + r) * 72 + nt * 16 + l16] = (_Float16)p;
      }
      for (int off = 1; off < 16; off <<= 1) sum += __shfl_xor(sum, off);
      l_r[r] = l_r[r] * alpha[r] + sum;
    }
    for (int ot = 0; ot < 8; ++ot)
      for (int r = 0; r < 4; ++r) o_acc[ot][r] *= alpha[r];

    // O += P @ V
    for (int ks = 0; ks < 2; ++ks) {
      const int sw = ((ks * 4 + quad) ^ (l16 & 7)) * 8;
      f16x8 ap = *(const f16x8*)&Ps[(wave * 16 + l16) * 72 + ks * 32 + quad * 8];
      for (int ot = 0; ot < 8; ++ot) {
        f16x8 bv = *(const f16x8*)&Vts[(ot * 16 + l16) * 64 + sw];
        o_acc[ot] = __builtin_amdgcn_mfma_f32_16x16x32_f16(ap, bv, o_acc[ot], 0, 0, 0);
      }
    }
    __syncthreads();
  }

  for (int ot = 0; ot < 8; ++ot)
    for (int r = 0; r < 4; ++r) {
      int m = q0 + wave * 16 + quad * 4 + r;
      O[(((size_t)b * Ll + m) * Hh + h) * Dd + ot * 16 + l16] =
          (_Float16)(o_acc[ot][r] / l_r[r]);
    }
}

// ---------------------------------------------------------------------------
extern "C" void kernel_launch(void* const* d_in, const int* in_sizes, int n_in,
                              void* d_out, int out_size, void* d_ws, size_t ws_size,
                              hipStream_t stream) {
  const float* inputs_q  = (const float*)d_in[0];
  const float* inputs_kv = (const float*)d_in[1];
  const float* bias      = (const float*)d_in[2];
  const float* rope_q    = (const float*)d_in[3];
  const float* rope_k    = (const float*)d_in[4];
  const float* Wq        = (const float*)d_in[5];
  const float* Wk        = (const float*)d_in[6];
  const float* Wv        = (const float*)d_in[7];
  const float* Wo        = (const float*)d_in[8];
  const float* q_scale   = (const float*)d_in[9];
  const float* k_scale   = (const float*)d_in[10];
  float* out = (float*)d_out;

  char* ws = (char*)d_ws;
  size_t o = 0;
  auto alloc = [&](size_t bytes) {
    char* p = ws + o;
    o += (bytes + 255) & ~(size_t)255;
    return p;
  };
  const size_t szX16 = (size_t)BL * Ee * 2;   // 16 MB
  const size_t szW16 = (size_t)Ee * Ee * 2;   // 8 MB
  _Float16* Xq_hi  = (_Float16*)alloc(szX16);
  _Float16* Xq_lo  = (_Float16*)alloc(szX16);
  _Float16* Xkv_hi = (_Float16*)alloc(szX16);
  _Float16* Xkv_lo = (_Float16*)alloc(szX16);
  _Float16* Wq_hi  = (_Float16*)alloc(szW16);
  _Float16* Wq_lo  = (_Float16*)alloc(szW16);
  _Float16* Wk_hi  = (_Float16*)alloc(szW16);
  _Float16* Wk_lo  = (_Float16*)alloc(szW16);
  _Float16* Wv_hi  = (_Float16*)alloc(szW16);
  _Float16* Wo_hi  = (_Float16*)alloc(szW16);
  float* Qraw = (float*)alloc((size_t)BL * Ee * 4);   // 32 MB
  float* Kraw = (float*)alloc((size_t)BL * Ee * 4);   // 32 MB
  _Float16* V16 = (_Float16*)alloc(szX16);
  // aliases (stream-ordered reuse; lifetimes disjoint)
  _Float16* Q16h   = Xq_hi;            // Xq dead after Q projection
  _Float16* Q16l   = Xq_lo;
  _Float16* K16h   = Xkv_hi;           // Xkv dead after K/V projections
  _Float16* K16l   = Xkv_lo;
  _Float16* X16    = (_Float16*)Qraw;  // Qraw dead after rmsrope(Q)
  _Float16* Vt_g   = Wq_hi;            // Wq hi+lo (16MB contig) dead after Q proj
  _Float16* bias16 = (_Float16*)Kraw;  // Kraw dead after rmsrope(K); 16.8MB <= 32MB

  const int nX4 = BL * Ee / 4;
  const int nW4 = Ee * Ee / 4;
  const int nB4 = Bb * Ll * Ll / 4;   // 2,097,152
  cvt_split<<<nX4 / 256, 256, 0, stream>>>(inputs_q, Xq_hi, Xq_lo, nX4);
  cvt_split<<<nX4 / 256, 256, 0, stream>>>(inputs_kv, Xkv_hi, Xkv_lo, nX4);
  cvt_split<<<nW4 / 256, 256, 0, stream>>>(Wq, Wq_hi, Wq_lo, nW4);
  cvt_split<<<nW4 / 256, 256, 0, stream>>>(Wk, Wk_hi, Wk_lo, nW4);
  cvt_f32_f16<<<nW4 / 256, 256, 0, stream>>>(Wv, Wv_hi, nW4);
  cvt_f32_f16<<<nW4 / 256, 256, 0, stream>>>(Wo, Wo_hi, nW4);

  dim3 gblk(Ee / 128, BL / 128);  // (16, 32)
  gemm_bt_split<<<gblk, 256, 0, stream>>>(Xq_hi, Xq_lo, Wq_hi, Wq_lo, Qraw, BL, Ee, Ee);
  gemm_bt_split<<<gblk, 256, 0, stream>>>(Xkv_hi, Xkv_lo, Wk_hi, Wk_lo, Kraw, BL, Ee, Ee);
  gemm_bt<_Float16><<<gblk, 256, 0, stream>>>(Xkv_hi, Wv_hi, V16, BL, Ee, Ee);

  transpose_v<<<dim3(BL / 64, Ee / 64), 256, 0, stream>>>(V16, Vt_g);

  rmsrope<<<BL * Hh / 4, 256, 0, stream>>>(Qraw, q_scale, rope_q, Q16h, Q16l, sqrtf((float)Dd));
  rmsrope<<<BL * Hh / 4, 256, 0, stream>>>(Kraw, k_scale, rope_k, K16h, K16l, 1.0f);

  // bias -> fp16 (into Kraw region, now dead)
  cvt_f32_f16<<<nB4 / 256, 256, 0, stream>>>(bias, bias16, nB4);

  attn<<<dim3(Hh, Ll / 128, Bb), 512, 0, stream>>>(Q16h, Q16l, K16h, K16l, Vt_g, bias16, X16);

  gemm_bt<float><<<gblk, 256, 0, stream>>>(X16, Wo_hi, out, BL, Ee, Ee);
}